// Round 6
// baseline (56.590 us; speedup 1.0000x reference)
//
#include <hip/hip_runtime.h>

typedef float f32x16 __attribute__((ext_vector_type(16)));
typedef short s16x8  __attribute__((ext_vector_type(8)));

#define B_SZ 4096
#define C_N  64
#define D_K  512
#define H_N  1024
#define MF   4            // 4 m-frags of 32 rows = 128 rows per chunk
#define TSTEPS 32         // 512 / 16
#define ZP_OFF_BYTES 32768

__device__ __forceinline__ short f2bf(float f){
  unsigned u = __float_as_uint(f);
  u += 0x7FFFu + ((u >> 16) & 1u);   // RTNE
  return (short)(u >> 16);
}
// A&S 7.1.26, |err| <= 1.5e-7
__device__ __forceinline__ float erf_fast(float x){
  float ax = fabsf(x);
  float t = __builtin_amdgcn_rcpf(1.0f + 0.3275911f * ax);
  float p = t * (0.254829592f + t * (-0.284496736f + t * (1.421413741f +
            t * (-1.453152027f + t * 1.061405429f))));
  float r = 1.0f - p * __expf(-ax * ax);
  return copysignf(r, x);
}
__device__ __forceinline__ float gelu_exact(float x){
  return 0.5f * x * (1.0f + erf_fast(x * 0.70710678118654752f));
}

// Fused count + scan + scatter + out-init. One block of 1024.
__global__ void k_prep(const int* __restrict__ cid, const float* __restrict__ b2,
                       int* __restrict__ offsets, int* __restrict__ bucket,
                       float* __restrict__ out){
  __shared__ int hist[C_N];
  const int tid = threadIdx.x;
  if (tid < C_N) hist[tid] = 0;
  __syncthreads();
  for (int i = tid; i < B_SZ; i += 1024) atomicAdd(&hist[cid[i]], 1);
  __syncthreads();
  if (tid < 64){
    int v = hist[tid];
    int x = v;
    #pragma unroll
    for (int d = 1; d < 64; d <<= 1){
      int y = __shfl_up(x, d, 64);
      if (tid >= d) x += y;
    }
    offsets[tid] = x - v;
    if (tid == 63) offsets[64] = x;
    hist[tid] = x - v;                  // reuse as cursor
  }
  __syncthreads();
  for (int i = tid; i < B_SZ; i += 1024){
    int c = cid[i];
    int p = atomicAdd(&hist[c], 1);
    bucket[p] = i;
    out[i] = b2[c];
  }
}

// Pack z into bucket-ordered bf16 rows: zp[slot][0..511]. 4 MB, L2/L3-resident.
__global__ void k_zpack(const float* __restrict__ z, const int* __restrict__ bucket,
                        short* __restrict__ zp){
  int u = blockIdx.x * 256 + threadIdx.x;     // 262144 units of 8 elems
  int slot = u >> 6;
  int k0 = (u & 63) * 8;
  const float* src = z + (size_t)bucket[slot] * D_K + k0;
  float4 a = *(const float4*)src;
  float4 b = *(const float4*)(src + 4);
  s16x8 v;
  v[0]=f2bf(a.x); v[1]=f2bf(a.y); v[2]=f2bf(a.z); v[3]=f2bf(a.w);
  v[4]=f2bf(b.x); v[5]=f2bf(b.y); v[6]=f2bf(b.z); v[7]=f2bf(b.w);
  *(s16x8*)(zp + ((size_t)slot << 9) + k0) = v;
}

__global__ __launch_bounds__(256, 2) void k_main(
    const short* __restrict__ zp, const float* __restrict__ W1,
    const float* __restrict__ b1, const float* __restrict__ W2,
    const int* __restrict__ offsets, const int* __restrict__ bucket,
    float* __restrict__ out)
{
  __shared__ float partial[128];
  // flat = slice*64 + c  -> flat%8 = c%8: company's 8 blocks share an XCD (zp L2 reuse)
  const int flat = blockIdx.x;
  const int c = flat & 63, slice = flat >> 6;      // 8 slices x 128 h
  const int off_c = offsets[c];
  const int n_c = offsets[c + 1] - off_c;
  if (n_c == 0) return;

  const int tid  = threadIdx.x;
  const int lane = tid & 63, wave = tid >> 6;      // 4 waves x 32 h
  const int l31 = lane & 31, lhi = lane >> 5;
  const int hcol = slice * 128 + wave * 32 + l31;  // h within company
  const float* Wc = W1 + (size_t)c * D_K * H_N + hcol;   // + k*1024
  const float b1v = b1[c * H_N + hcol];
  const float w2v = W2[c * H_N + hcol];

  for (int rb = 0; rb < n_c; rb += 128){           // 1 iteration in practice
    if (tid < 128) partial[tid] = 0.0f;
    __syncthreads();

    // ---- W1 prologue: DEPTH=4 k-steps x 8 rows, 32 independent dword loads ----
    float fb[4][8];
    #pragma unroll
    for (int s = 0; s < 4; ++s){
      #pragma unroll
      for (int e = 0; e < 8; ++e)
        fb[s][e] = Wc[(size_t)(s * 16 + lhi * 8 + e) * H_N];
    }

    // ---- A prologue: frags for t=0 (zp is bf16, no conversion needed) ----
    s16x8 af[2][MF];
    #pragma unroll
    for (int m = 0; m < MF; ++m){
      int row = rb + m * 32 + l31;
      af[0][m] = (row < n_c)
        ? *(const s16x8*)(zp + ((size_t)(off_c + row) << 9) + lhi * 8)
        : (s16x8)0;
    }

    f32x16 acc[MF];
    #pragma unroll
    for (int m = 0; m < MF; ++m) acc[m] = 0;

    // ---- barrier-free K loop: 32 steps of k=16 ----
    #pragma unroll 4
    for (int t = 0; t < TSTEPS; ++t){
      const int sl = t & 3, cur = t & 1;
      s16x8 bf;
      #pragma unroll
      for (int e = 0; e < 8; ++e) bf[e] = f2bf(fb[sl][e]);
      if (t < TSTEPS - 1){                 // prefetch A for t+1
        #pragma unroll
        for (int m = 0; m < MF; ++m){
          int row = rb + m * 32 + l31;
          af[cur ^ 1][m] = (row < n_c)
            ? *(const s16x8*)(zp + ((size_t)(off_c + row) << 9) + (t + 1) * 16 + lhi * 8)
            : (s16x8)0;
        }
      }
      if (t < TSTEPS - 4){                 // refill W1 pipeline slot for t+4
        #pragma unroll
        for (int e = 0; e < 8; ++e)
          fb[sl][e] = Wc[(size_t)((t + 4) * 16 + lhi * 8 + e) * H_N];
      }
      #pragma unroll
      for (int m = 0; m < MF; ++m)
        acc[m] = __builtin_amdgcn_mfma_f32_32x32x16_bf16(af[cur][m], bf, acc[m], 0, 0, 0);
    }

    // ---- epilogue: GELU + W2 dot, 32-lane reduce, LDS partial, flush ----
    #pragma unroll
    for (int m = 0; m < MF; ++m){
      #pragma unroll
      for (int r = 0; r < 16; ++r){
        int row = rb + m * 32 + (r & 3) + 8 * (r >> 2) + 4 * lhi;
        float s = gelu_exact(acc[m][r] + b1v) * w2v;
        s += __shfl_xor(s, 1, 64);
        s += __shfl_xor(s, 2, 64);
        s += __shfl_xor(s, 4, 64);
        s += __shfl_xor(s, 8, 64);
        s += __shfl_xor(s, 16, 64);
        if (l31 == 0 && row < n_c)
          atomicAdd(&partial[row - rb], s);
      }
    }
    __syncthreads();
    int rows = n_c - rb; if (rows > 128) rows = 128;
    for (int r = tid; r < rows; r += 256)
      atomicAdd(&out[bucket[off_c + rb + r]], partial[r]);
    __syncthreads();
  }
}

extern "C" void kernel_launch(void* const* d_in, const int* in_sizes, int n_in,
                              void* d_out, int out_size, void* d_ws, size_t ws_size,
                              hipStream_t stream){
  const float* z  = (const float*)d_in[0];
  const int*   cid= (const int*)  d_in[1];
  const float* W1 = (const float*)d_in[2];
  const float* b1 = (const float*)d_in[3];
  const float* W2 = (const float*)d_in[4];
  const float* b2 = (const float*)d_in[5];
  float* out = (float*)d_out;

  int*   ws      = (int*)d_ws;
  int*   offsets = ws;                                   // [65]
  int*   bucket  = ws + 128;                             // [4096]
  short* zp      = (short*)((char*)d_ws + ZP_OFF_BYTES); // [4096*512] bf16 = 4 MB

  k_prep <<<1, 1024, 0, stream>>>(cid, b2, offsets, bucket, out);
  k_zpack<<<1024, 256, 0, stream>>>(z, bucket, zp);
  k_main <<<C_N * 8, 256, 0, stream>>>(zp, W1, b1, W2, offsets, bucket, out);
}